// Round 13
// baseline (200.667 us; speedup 1.0000x reference)
//
#include <hip/hip_runtime.h>

// GCN 2-layer forward — R27 = R25 base + scalarized pullg edge-walk.
// R26 adjudicated: fill halved (FETCH 68->30.5MB) but pullg 35->47.5us with
// VALU 56->74% — pullg is VALU-ISSUE bound, tracks instr/edge not bytes.
// The per-edge scalar work (ssrc load, dinv gather, weight, mask, 64b addr)
// was replicated across 32 feature-lanes. R27: ONE NODE PER WAVE (64 lanes
// x 4B = full 256B row). start/len/rec wave-uniform; srec[e]=src|bf16(dinv
// [src])<<16 prebuilt by k_wgt (into dead tmp); rec pinned to SGPR via
// readfirstlane -> weight/addr on scalar pipe; VALU/edge = 1 load + 2
// unpack + 2 fmaf. Exact len kills lenMax divergence. 512-thr blocks keep
// gemm2 epilogue identical. bf16 h restored; rest verbatim R25 (172.07).
// Session rules: boundary ~1us (R9); serial global loops poison (R11); bulk
// random atomic scatter poison (R18-rev); gather depth/coalescing/fill all
// non-binding (R24/R25/R26) — VALU instr count IS binding (R26).

typedef unsigned int uint32;
typedef unsigned short u16;
typedef __attribute__((ext_vector_type(8))) short bf16x8;
typedef __attribute__((ext_vector_type(4))) float f32x4;

#define NBMAX 1024
#define CHUNK 2048
#define EH 8192   // edges per hist block

__device__ inline u16 bf16rn(float f) {
    unsigned u = __float_as_uint(f);
    return (u16)((u + 0x7fffu + ((u >> 16) & 1u)) >> 16);
}

__device__ inline void bffma(float2& a, float w, uint32 u) {
    a.x = fmaf(w, __uint_as_float(u << 16), a.x);
    a.y = fmaf(w, __uint_as_float(u & 0xffff0000u), a.y);
}

// ---- L1: gemm1 tiles || hist blocks (LDS hist -> global gh atomics) -------
__global__ __launch_bounds__(256) void k_combo(
    const float* __restrict__ x, const float* __restrict__ W1,
    const int* __restrict__ dstv, int* __restrict__ gh,
    u16* __restrict__ h, int N, int E, int NB, int ntile)
{
    __shared__ __align__(16) unsigned char smem[128 * 136 * 2];  // 34816 B
    int t = threadIdx.x;

    if ((int)blockIdx.x >= ntile) {
        int* hl = (int*)smem;
        int hb = blockIdx.x - ntile;
        int e0 = hb * EH, e1 = min(e0 + EH, E);
        for (int i = t; i < NB; i += 256) hl[i] = 0;
        __syncthreads();
        for (int e = e0 + t; e < e1; e += 256)
            atomicAdd(&hl[dstv[e] >> 8], 1);
        __syncthreads();
        for (int i = t; i < NB; i += 256) {
            int c = hl[i];
            if (c) atomicAdd(&gh[i], c);   // ~196 device atomics/block (cheap)
        }
        return;
    }

    // gemm1: h[N,128](bf16) = x @ W1, MFMA 16x16x32, operands swapped:
    // D[feature][node]; lane owns node=rowbase+ln, features ct*16+quad*4+i.
    u16* Wl = (u16*)smem;  // [n][k] pitch 136 (2-way bank aliasing: free)
    const float4* Wg4 = (const float4*)W1;
    for (int g = t; g < 128 * 32; g += 256) {
        int k = g >> 5, n4 = (g & 31) * 4;
        float4 v = Wg4[g];
        Wl[(n4 + 0) * 136 + k] = bf16rn(v.x);
        Wl[(n4 + 1) * 136 + k] = bf16rn(v.y);
        Wl[(n4 + 2) * 136 + k] = bf16rn(v.z);
        Wl[(n4 + 3) * 136 + k] = bf16rn(v.w);
    }
    __syncthreads();

    int wave = t >> 6, lane = t & 63;
    int quad = lane >> 4, ln = lane & 15;
    int rowbase = blockIdx.x * 64 + wave * 16;
    int node = rowbase + ln;
    int rclamp = min(node, N - 1);

    f32x4 acc[8];
    #pragma unroll
    for (int ct = 0; ct < 8; ++ct) acc[ct] = (f32x4){0.f, 0.f, 0.f, 0.f};

    #pragma unroll
    for (int q = 0; q < 4; ++q) {
        const float4* xr = (const float4*)(x + (size_t)rclamp * 128 + q * 32 + quad * 8);
        float4 a0 = xr[0], a1 = xr[1];
        bf16x8 xfr;   // B-operand: col=node(ln), k = q*32 + quad*8 + e
        xfr[0] = (short)bf16rn(a0.x); xfr[1] = (short)bf16rn(a0.y);
        xfr[2] = (short)bf16rn(a0.z); xfr[3] = (short)bf16rn(a0.w);
        xfr[4] = (short)bf16rn(a1.x); xfr[5] = (short)bf16rn(a1.y);
        xfr[6] = (short)bf16rn(a1.z); xfr[7] = (short)bf16rn(a1.w);
        #pragma unroll
        for (int ct = 0; ct < 8; ++ct) {
            // A-operand: row=feature-in-block(ln), k = q*32 + quad*8 + e
            bf16x8 wfr = *(const bf16x8*)&Wl[(ct * 16 + ln) * 136 + q * 32 + quad * 8];
            acc[ct] = __builtin_amdgcn_mfma_f32_16x16x32_bf16(wfr, xfr, acc[ct], 0, 0, 0);
        }
    }
    if (node < N) {
        u16* hp = h + (size_t)node * 128 + quad * 4;
        #pragma unroll
        for (int ct = 0; ct < 8; ++ct) {
            uint2 v;
            v.x = (uint32)bf16rn(acc[ct][0]) | ((uint32)bf16rn(acc[ct][1]) << 16);
            v.y = (uint32)bf16rn(acc[ct][2]) | ((uint32)bf16rn(acc[ct][3]) << 16);
            *(uint2*)(hp + ct * 16) = v;
        }
    }
}

// ---- L2: exclusive scan of gh via shfl wave-scan (2 barriers) -------------
__global__ __launch_bounds__(1024) void k_scanB(
    const int* __restrict__ gh, int* __restrict__ bbase,
    int* __restrict__ bfill, int NB, int E)
{
    __shared__ int wsum[16];
    int t = threadIdx.x;
    int lane = t & 63, wv = t >> 6;
    int v = (t < NB) ? gh[t] : 0;
    int sc = v;
    #pragma unroll
    for (int off = 1; off < 64; off <<= 1) {
        int u = __shfl_up(sc, off);
        if (lane >= off) sc += u;
    }
    if (lane == 63) wsum[wv] = sc;
    __syncthreads();
    if (wv == 0 && lane < 16) {
        int b = wsum[lane];
        int bs = b;
        #pragma unroll
        for (int off = 1; off < 16; off <<= 1) {
            int u = __shfl_up(bs, off);
            if (lane >= off) bs += u;
        }
        wsum[lane] = bs - b;   // exclusive prefix of wave sums
    }
    __syncthreads();
    int incl = sc + wsum[wv];
    if (t < NB) {
        bbase[t] = incl - v;
        bfill[t] = 0;
    }
    if (t == 0) bbase[NB] = E;
}

// ---- L3: partition edges into bucket regions (512 thr, CHUNK 2048) --------
__global__ __launch_bounds__(512) void k_partition(
    const int* __restrict__ src, const int* __restrict__ dstv,
    const int* __restrict__ bbase, int* __restrict__ bfill,
    uint32* __restrict__ tmp, int E, int NB)
{
    __shared__ int cntL[NBMAX];
    __shared__ int baseL[NBMAX];
    int t = threadIdx.x;
    int e0 = blockIdx.x * CHUNK;
    int e1 = min(e0 + CHUNK, E);
    for (int i = t; i < NB; i += 512) cntL[i] = 0;
    __syncthreads();
    for (int e = e0 + t; e < e1; e += 512)
        atomicAdd(&cntL[dstv[e] >> 8], 1);
    __syncthreads();
    for (int i = t; i < NB; i += 512) {
        int cc = cntL[i];
        baseL[i] = cc ? bbase[i] + atomicAdd(&bfill[i], cc) : 0;
        cntL[i] = 0;
    }
    __syncthreads();
    for (int e = e0 + t; e < e1; e += 512) {
        int sv = src[e], d = dstv[e];
        int b = d >> 8;
        int r = atomicAdd(&cntL[b], 1);
        tmp[baseL[b] + r] = (uint32)sv | ((uint32)(d & 255) << 16);
    }
}

// ---- L4: per-bucket exact sort (1024 threads); emit dinv / rs / ssrc ------
__global__ __launch_bounds__(1024) void k_bsort(
    const uint32* __restrict__ tmp, const int* __restrict__ bbase,
    u16* __restrict__ ssrc, int* __restrict__ rs,
    float* __restrict__ dinv, int N)
{
    __shared__ int cnt[256];
    __shared__ int ofs[256];
    int t = threadIdx.x;
    int b = blockIdx.x;
    int base = bbase[b];
    int endb = bbase[b + 1];
    int node0 = b << 8;

    if (t < 256) cnt[t] = 0;
    __syncthreads();
    for (int i = base + t; i < endb; i += 1024)
        atomicAdd(&cnt[(tmp[i] >> 16) & 255], 1);
    __syncthreads();
    int v = (t < 256) ? cnt[t] : 0;
    __syncthreads();
    for (int off = 1; off < 256; off <<= 1) {
        int u = (t >= off && t < 256) ? cnt[t - off] : 0;
        __syncthreads();
        if (t < 256) cnt[t] += u;
        __syncthreads();
    }
    if (t < 256) {
        int node = node0 + t;
        if (node < N) {
            dinv[node] = rsqrtf(fmaxf((float)v, 1.0f));
            rs[node] = base + cnt[t];
        }
        ofs[t] = base + cnt[t] - v;
    }
    __syncthreads();
    for (int i = base + t; i < endb; i += 1024) {
        uint32 rec = tmp[i];
        int pos = atomicAdd(&ofs[(rec >> 16) & 255], 1);
        ssrc[pos] = (u16)(rec & 0xffffu);
    }
}

// ---- L4b: srec[e] = src | bf16(dinv[src])<<16 (into dead tmp) -------------
__global__ __launch_bounds__(256) void k_wgt(
    const u16* __restrict__ ssrc, const float* __restrict__ dinv,
    uint32* __restrict__ srec, int E)
{
    int i = blockIdx.x * 256 + threadIdx.x;
    if (i >= E) return;
    uint32 s = ssrc[i];
    srec[i] = s | ((uint32)bf16rn(dinv[s]) << 16);
}

// ---- L5: pullg — 1 node/wave, scalarized edge walk, fused gemm2 -----------
__global__ __launch_bounds__(512) void k_pullg(
    const int* __restrict__ rs, const uint32* __restrict__ srec,
    const float* __restrict__ dinv, const uint32* __restrict__ h32,
    const float* __restrict__ b1, const float* __restrict__ W2,
    u16* __restrict__ h2, int N)
{
    __shared__ float W2T[16 * 132];   // [f][k] pitch 132
    __shared__ float rowbuf[8 * 132]; // [r][k] pitch 132 (float4 pitch 33)
    int t = threadIdx.x;

    for (int g = t; g < 2048; g += 512) {
        int k = g >> 4, f = g & 15;
        W2T[f * 132 + k] = W2[g];
    }

    int wave = t >> 6, lane = t & 63;
    int n = blockIdx.x * 8 + wave;    // ONE node per wave
    bool valid = (n < N);
    int nc = valid ? n : 0;
    int start = (nc == 0) ? 0 : rs[nc - 1];
    int len   = valid ? (rs[nc] - start) : 0;
    float dn  = valid ? dinv[nc] : 0.f;

    // lane owns features {2*lane, 2*lane+1}: h row = 64 lanes x 4B = 256B
    float2 a0 = {0.f, 0.f}, a1 = {0.f, 0.f}, a2 = {0.f, 0.f}, a3 = {0.f, 0.f};

    for (int tt = 0; tt < len; tt += 4) {
        int last = len - 1;
        uint32 r0 = srec[start + tt];
        uint32 r1 = srec[start + min(tt + 1, last)];
        uint32 r2 = srec[start + min(tt + 2, last)];
        uint32 r3 = srec[start + min(tt + 3, last)];
        // pin to SGPRs: weight/addr math moves to the scalar pipe
        r0 = __builtin_amdgcn_readfirstlane(r0);
        r1 = __builtin_amdgcn_readfirstlane(r1);
        r2 = __builtin_amdgcn_readfirstlane(r2);
        r3 = __builtin_amdgcn_readfirstlane(r3);
        uint32 u0 = h32[(size_t)(r0 & 0xffffu) * 64 + lane];
        uint32 u1 = h32[(size_t)(r1 & 0xffffu) * 64 + lane];
        uint32 u2 = h32[(size_t)(r2 & 0xffffu) * 64 + lane];
        uint32 u3 = h32[(size_t)(r3 & 0xffffu) * 64 + lane];
        float w0 = __uint_as_float(r0 & 0xffff0000u);
        float w1 = (tt + 1 < len) ? __uint_as_float(r1 & 0xffff0000u) : 0.f;
        float w2 = (tt + 2 < len) ? __uint_as_float(r2 & 0xffff0000u) : 0.f;
        float w3 = (tt + 3 < len) ? __uint_as_float(r3 & 0xffff0000u) : 0.f;
        bffma(a0, w0, u0);
        bffma(a1, w1, u1);
        bffma(a2, w2, u2);
        bffma(a3, w3, u3);
    }

    {
        float sx = (a0.x + a1.x) + (a2.x + a3.x);
        float sy = (a0.y + a1.y) + (a2.y + a3.y);
        float2 bb = ((const float2*)b1)[lane];
        float2 v;
        v.x = fmaxf(fmaf(dn, sx, bb.x), 0.f);
        v.y = fmaxf(fmaf(dn, sy, bb.y), 0.f);
        ((float2*)rowbuf)[wave * 66 + lane] = v;   // pitch 132 floats
    }
    __syncthreads();

    if (t < 128) {
        int f = t & 15, r = t >> 4;
        const float4* W4 = (const float4*)W2T;
        const float4* rb4 = (const float4*)rowbuf;
        float acc = 0.f;
        #pragma unroll 8
        for (int k4 = 0; k4 < 32; ++k4) {
            float4 w = W4[f * 33 + k4];
            float4 xv = rb4[r * 33 + k4];
            acc = fmaf(xv.x, w.x, acc);
            acc = fmaf(xv.y, w.y, acc);
            acc = fmaf(xv.z, w.z, acc);
            acc = fmaf(xv.w, w.w, acc);
        }
        int rn = blockIdx.x * 8 + r;
        if (rn < N) h2[(size_t)rn * 16 + f] = bf16rn(acc);
    }
}

// ---- L6: pull2 + log_softmax, 4-deep unroll -------------------------------
__global__ __launch_bounds__(256) void k_pull2(
    const int* __restrict__ rs, const u16* __restrict__ ssrc,
    const float* __restrict__ dinv, const uint32* __restrict__ h2,
    const float* __restrict__ b2, float* __restrict__ out, int N)
{
    int idx = blockIdx.x * 256 + threadIdx.x;
    int n = idx >> 3;
    if (n >= N) return;
    int c = idx & 7;
    int start = (n == 0) ? 0 : rs[n - 1];
    int len = rs[n] - start;
    float dn = dinv[n];

    float2 a[4];
    #pragma unroll
    for (int k = 0; k < 4; ++k) a[k] = (float2){0.f, 0.f};

    for (int tt = 0; tt < len; tt += 4) {
        int s[4];
        uint32 u[4];
        float w[4];
        #pragma unroll
        for (int k = 0; k < 4; ++k) {
            bool act = (tt + k) < len;
            int jj = act ? (start + tt + k) : 0;   // index 0 always valid
            s[k] = (int)ssrc[jj];
            w[k] = act ? 1.f : 0.f;
        }
        #pragma unroll
        for (int k = 0; k < 4; ++k)
            u[k] = h2[(size_t)s[k] * 8 + c];
        #pragma unroll
        for (int k = 0; k < 4; ++k)
            w[k] *= dn * dinv[s[k]];
        #pragma unroll
        for (int k = 0; k < 4; ++k)
            bffma(a[k], w[k], u[k]);
    }

    float acc0 = (a[0].x + a[1].x) + (a[2].x + a[3].x);
    float acc1 = (a[0].y + a[1].y) + (a[2].y + a[3].y);
    float v0 = acc0 + b2[2 * c];
    float v1 = acc1 + b2[2 * c + 1];
    float m = fmaxf(v0, v1);
    #pragma unroll
    for (int off = 1; off < 8; off <<= 1) m = fmaxf(m, __shfl_xor(m, off));
    float s = expf(v0 - m) + expf(v1 - m);
    #pragma unroll
    for (int off = 1; off < 8; off <<= 1) s += __shfl_xor(s, off);
    float ls = logf(s);
    float2 r = {v0 - m - ls, v1 - m - ls};
    ((float2*)out)[(size_t)n * 8 + c] = r;
}

extern "C" void kernel_launch(void* const* d_in, const int* in_sizes, int n_in,
                              void* d_out, int out_size, void* d_ws, size_t ws_size,
                              hipStream_t stream) {
    const float* x  = (const float*)d_in[0];
    const int*   ei = (const int*)d_in[1];
    const float* W1 = (const float*)d_in[2];
    const float* b1 = (const float*)d_in[3];
    const float* W2 = (const float*)d_in[4];
    const float* b2 = (const float*)d_in[5];
    float* outp = (float*)d_out;

    const int E = in_sizes[1] / 2;
    const int N = in_sizes[0] / 128;   // N=50000 (fits u16 src packing)
    const int NB = (N + 255) >> 8;
    const int NH = (E + EH - 1) / EH;
    const int ntile = (N + 63) / 64;
    const int* src  = ei;
    const int* dstv = ei + E;

    const int Npad = (N + 255) & ~255;
    const int Epad = (E + 255) & ~255;
    int*   gh    = (int*)d_ws;                      // [NBMAX] global hist
    int*   bbase = gh + NBMAX;                      // [NBMAX+1] (+pad)
    int*   bfill = bbase + NBMAX + 256;             // [NBMAX]
    int*   rs    = bfill + NBMAX;                   // [Npad]
    float* dinv  = (float*)(rs + Npad);             // [Npad]
    uint32* tmp  = (uint32*)(dinv + Npad);          // [Epad]; srec after bsort
    u16*   ssrc  = (u16*)(tmp + Epad);              // [Epad] u16
    uintptr_t hp = ((uintptr_t)(ssrc + Epad) + 255) & ~(uintptr_t)255;
    u16*   h     = (u16*)hp;                        // [Npad*128] bf16
    u16*   h2    = h + (size_t)Npad * 128;          // [Npad*16] bf16

    hipMemsetAsync(gh, 0, NBMAX * sizeof(int), stream);
    k_combo<<<ntile + NH, 256, 0, stream>>>(x, W1, dstv, gh, h, N, E, NB, ntile);
    k_scanB<<<1, 1024, 0, stream>>>(gh, bbase, bfill, NB, E);
    k_partition<<<(E + CHUNK - 1) / CHUNK, 512, 0, stream>>>(src, dstv, bbase,
                                                             bfill, tmp, E, NB);
    k_bsort<<<NB, 1024, 0, stream>>>(tmp, bbase, ssrc, rs, dinv, N);
    k_wgt<<<(E + 255) / 256, 256, 0, stream>>>(ssrc, dinv, tmp, E);
    k_pullg<<<(N + 7) / 8, 512, 0, stream>>>(rs, (const uint32*)tmp, dinv,
                                             (const uint32*)h, b1, W2, h2, N);
    k_pull2<<<(N * 8 + 255) / 256, 256, 0, stream>>>(rs, ssrc, dinv,
                                                     (const uint32*)h2, b2, outp, N);
}

// Round 14
// 168.776 us; speedup vs baseline: 1.1890x; 1.1890x over previous
//
#include <hip/hip_runtime.h>

// GCN 2-layer forward — R28 = R25 base + combo tail/staging fix.
// R27 FAIL (200.7): wave-scalarized pullg traded VALU for a serial
// srec->readfirstlane->load chain (VALU 39%, latency-bound, 59us). pullg
// variants exhausted: 4deep/2node=35, 8deep=35, uint4=37, fp8=47(VALU),
// wave-scalar=59(latency) => R25 pullg is the floor; reverted, frozen.
// Meta-lesson R21-R27: all big blocks are LATENCY-bound at modest occupancy;
// shaving bytes/VALU/conflicts is null. Only parallelism-shaped changes paid
// (R20). Last untested theory = combo (46us, all pipes idle):
//   a) hist blocks moved FIRST (idx<NH): they previously dispatched last ->
//      serial tail after gemm retires (~5-10us suspect).
//   b) 128-row gemm tiles: W1 (64KB) re-staged per block with 16-way-
//      conflicted LDS writes; halving block count 782->391 halves staging.
// Pred: combo 46->36-40, total ~162-167; if null -> plateau declaration.
// Session rules: boundary ~1us (R9); serial global loops poison (R11); bulk
// random atomic scatter poison (R18-rev); latency-bound blocks insensitive
// to busy-work reduction (R21/R24/R25/R26/R27).

typedef unsigned int uint32;
typedef unsigned short u16;
typedef __attribute__((ext_vector_type(8))) short bf16x8;
typedef __attribute__((ext_vector_type(4))) float f32x4;

#define NBMAX 1024
#define CHUNK 2048
#define EH 8192   // edges per hist block

__device__ inline u16 bf16rn(float f) {
    unsigned u = __float_as_uint(f);
    return (u16)((u + 0x7fffu + ((u >> 16) & 1u)) >> 16);
}

__device__ inline void bffma(float2& a, float w, uint32 u) {
    a.x = fmaf(w, __uint_as_float(u << 16), a.x);
    a.y = fmaf(w, __uint_as_float(u & 0xffff0000u), a.y);
}

// ---- L1: hist blocks FIRST || gemm1 128-row tiles -------------------------
__global__ __launch_bounds__(256) void k_combo(
    const float* __restrict__ x, const float* __restrict__ W1,
    const int* __restrict__ dstv, int* __restrict__ gh,
    u16* __restrict__ h, int N, int E, int NB, int NH)
{
    __shared__ __align__(16) unsigned char smem[128 * 136 * 2];  // 34816 B
    int t = threadIdx.x;

    if ((int)blockIdx.x < NH) {        // hist blocks first: co-run with gemm
        int* hl = (int*)smem;
        int hb = blockIdx.x;
        int e0 = hb * EH, e1 = min(e0 + EH, E);
        for (int i = t; i < NB; i += 256) hl[i] = 0;
        __syncthreads();
        for (int e = e0 + t; e < e1; e += 256)
            atomicAdd(&hl[dstv[e] >> 8], 1);
        __syncthreads();
        for (int i = t; i < NB; i += 256) {
            int c = hl[i];
            if (c) atomicAdd(&gh[i], c);   // ~196 device atomics/block (cheap)
        }
        return;
    }

    // gemm1: h[N,128](bf16) = x @ W1, MFMA 16x16x32, operands swapped:
    // D[feature][node]; lane owns node=rowbase+ln, features ct*16+quad*4+i.
    // 128-row tile = two 64-row halves sharing ONE W staging.
    u16* Wl = (u16*)smem;  // [n][k] pitch 136 (2-way bank aliasing: free)
    const float4* Wg4 = (const float4*)W1;
    for (int g = t; g < 128 * 32; g += 256) {
        int k = g >> 5, n4 = (g & 31) * 4;
        float4 v = Wg4[g];
        Wl[(n4 + 0) * 136 + k] = bf16rn(v.x);
        Wl[(n4 + 1) * 136 + k] = bf16rn(v.y);
        Wl[(n4 + 2) * 136 + k] = bf16rn(v.z);
        Wl[(n4 + 3) * 136 + k] = bf16rn(v.w);
    }
    __syncthreads();

    int wave = t >> 6, lane = t & 63;
    int quad = lane >> 4, ln = lane & 15;
    int tile0 = (blockIdx.x - NH) * 128;

    #pragma unroll 1
    for (int half = 0; half < 2; ++half) {
        int rowbase = tile0 + half * 64 + wave * 16;
        int node = rowbase + ln;
        int rclamp = min(node, N - 1);

        f32x4 acc[8];
        #pragma unroll
        for (int ct = 0; ct < 8; ++ct) acc[ct] = (f32x4){0.f, 0.f, 0.f, 0.f};

        #pragma unroll
        for (int q = 0; q < 4; ++q) {
            const float4* xr = (const float4*)(x + (size_t)rclamp * 128 + q * 32 + quad * 8);
            float4 a0 = xr[0], a1 = xr[1];
            bf16x8 xfr;   // B-operand: col=node(ln), k = q*32 + quad*8 + e
            xfr[0] = (short)bf16rn(a0.x); xfr[1] = (short)bf16rn(a0.y);
            xfr[2] = (short)bf16rn(a0.z); xfr[3] = (short)bf16rn(a0.w);
            xfr[4] = (short)bf16rn(a1.x); xfr[5] = (short)bf16rn(a1.y);
            xfr[6] = (short)bf16rn(a1.z); xfr[7] = (short)bf16rn(a1.w);
            #pragma unroll
            for (int ct = 0; ct < 8; ++ct) {
                // A-operand: row=feature-in-block(ln), k = q*32 + quad*8 + e
                bf16x8 wfr = *(const bf16x8*)&Wl[(ct * 16 + ln) * 136 + q * 32 + quad * 8];
                acc[ct] = __builtin_amdgcn_mfma_f32_16x16x32_bf16(wfr, xfr, acc[ct], 0, 0, 0);
            }
        }
        if (node < N) {
            u16* hp = h + (size_t)node * 128 + quad * 4;
            #pragma unroll
            for (int ct = 0; ct < 8; ++ct) {
                uint2 v;
                v.x = (uint32)bf16rn(acc[ct][0]) | ((uint32)bf16rn(acc[ct][1]) << 16);
                v.y = (uint32)bf16rn(acc[ct][2]) | ((uint32)bf16rn(acc[ct][3]) << 16);
                *(uint2*)(hp + ct * 16) = v;
            }
        }
    }
}

// ---- L2: exclusive scan of gh via shfl wave-scan (2 barriers) -------------
__global__ __launch_bounds__(1024) void k_scanB(
    const int* __restrict__ gh, int* __restrict__ bbase,
    int* __restrict__ bfill, int NB, int E)
{
    __shared__ int wsum[16];
    int t = threadIdx.x;
    int lane = t & 63, wv = t >> 6;
    int v = (t < NB) ? gh[t] : 0;
    int sc = v;
    #pragma unroll
    for (int off = 1; off < 64; off <<= 1) {
        int u = __shfl_up(sc, off);
        if (lane >= off) sc += u;
    }
    if (lane == 63) wsum[wv] = sc;
    __syncthreads();
    if (wv == 0 && lane < 16) {
        int b = wsum[lane];
        int bs = b;
        #pragma unroll
        for (int off = 1; off < 16; off <<= 1) {
            int u = __shfl_up(bs, off);
            if (lane >= off) bs += u;
        }
        wsum[lane] = bs - b;   // exclusive prefix of wave sums
    }
    __syncthreads();
    int incl = sc + wsum[wv];
    if (t < NB) {
        bbase[t] = incl - v;
        bfill[t] = 0;
    }
    if (t == 0) bbase[NB] = E;
}

// ---- L3: partition edges into bucket regions (512 thr, CHUNK 2048) --------
__global__ __launch_bounds__(512) void k_partition(
    const int* __restrict__ src, const int* __restrict__ dstv,
    const int* __restrict__ bbase, int* __restrict__ bfill,
    uint32* __restrict__ tmp, int E, int NB)
{
    __shared__ int cntL[NBMAX];
    __shared__ int baseL[NBMAX];
    int t = threadIdx.x;
    int e0 = blockIdx.x * CHUNK;
    int e1 = min(e0 + CHUNK, E);
    for (int i = t; i < NB; i += 512) cntL[i] = 0;
    __syncthreads();
    for (int e = e0 + t; e < e1; e += 512)
        atomicAdd(&cntL[dstv[e] >> 8], 1);
    __syncthreads();
    for (int i = t; i < NB; i += 512) {
        int cc = cntL[i];
        baseL[i] = cc ? bbase[i] + atomicAdd(&bfill[i], cc) : 0;
        cntL[i] = 0;
    }
    __syncthreads();
    for (int e = e0 + t; e < e1; e += 512) {
        int sv = src[e], d = dstv[e];
        int b = d >> 8;
        int r = atomicAdd(&cntL[b], 1);
        tmp[baseL[b] + r] = (uint32)sv | ((uint32)(d & 255) << 16);
    }
}

// ---- L4: per-bucket exact sort (1024 threads); emit dinv / rs / ssrc ------
__global__ __launch_bounds__(1024) void k_bsort(
    const uint32* __restrict__ tmp, const int* __restrict__ bbase,
    u16* __restrict__ ssrc, int* __restrict__ rs,
    float* __restrict__ dinv, int N)
{
    __shared__ int cnt[256];
    __shared__ int ofs[256];
    int t = threadIdx.x;
    int b = blockIdx.x;
    int base = bbase[b];
    int endb = bbase[b + 1];
    int node0 = b << 8;

    if (t < 256) cnt[t] = 0;
    __syncthreads();
    for (int i = base + t; i < endb; i += 1024)
        atomicAdd(&cnt[(tmp[i] >> 16) & 255], 1);
    __syncthreads();
    int v = (t < 256) ? cnt[t] : 0;
    __syncthreads();
    for (int off = 1; off < 256; off <<= 1) {
        int u = (t >= off && t < 256) ? cnt[t - off] : 0;
        __syncthreads();
        if (t < 256) cnt[t] += u;
        __syncthreads();
    }
    if (t < 256) {
        int node = node0 + t;
        if (node < N) {
            dinv[node] = rsqrtf(fmaxf((float)v, 1.0f));
            rs[node] = base + cnt[t];
        }
        ofs[t] = base + cnt[t] - v;
    }
    __syncthreads();
    for (int i = base + t; i < endb; i += 1024) {
        uint32 rec = tmp[i];
        int pos = atomicAdd(&ofs[(rec >> 16) & 255], 1);
        ssrc[pos] = (u16)(rec & 0xffffu);
    }
}

// ---- L5: pullg — fused pull1 + gemm2; 8-deep gather (R25 form, frozen) ----
__global__ __launch_bounds__(256) void k_pullg(
    const int* __restrict__ rs, const u16* __restrict__ ssrc,
    const float* __restrict__ dinv, const uint2* __restrict__ h,
    const float* __restrict__ b1, const float* __restrict__ W2,
    u16* __restrict__ h2, int N)
{
    __shared__ float W2T[16 * 132];   // [f][k] pitch 132
    __shared__ float rowbuf[8 * 132]; // [r][k] pitch 132 (float4 pitch 33)
    int t = threadIdx.x;

    for (int g = t; g < 2048; g += 256) {
        int k = g >> 4, f = g & 15;
        W2T[f * 132 + k] = W2[g];
    }

    int wave = t >> 6, lane = t & 63;
    int sub = lane >> 5;
    int rl = lane & 31;
    int rowbase = blockIdx.x * 8;
    int n = rowbase + wave * 2 + sub;
    bool valid = (n < N);
    int nc = valid ? n : 0;
    int start = valid ? ((nc == 0) ? 0 : rs[nc - 1]) : 0;
    int len   = valid ? (rs[nc] - start) : 0;
    float dn  = valid ? dinv[nc] : 0.f;
    int lenMax = max(len, __shfl_xor(len, 32));

    float2 aA[4], aB[4];
    #pragma unroll
    for (int k = 0; k < 4; ++k) {
        aA[k] = (float2){0.f, 0.f};
        aB[k] = (float2){0.f, 0.f};
    }

    for (int tt = 0; tt < lenMax; tt += 8) {
        int s[8];
        uint2 u[8];
        float w[8];
        #pragma unroll
        for (int k = 0; k < 8; ++k) {
            bool act = (tt + k) < len;
            int jj = act ? (start + tt + k) : 0;   // index 0 always valid
            s[k] = (int)ssrc[jj];
            w[k] = act ? 1.f : 0.f;
        }
        #pragma unroll
        for (int k = 0; k < 8; ++k)
            u[k] = h[(size_t)s[k] * 32 + rl];      // 8 gathers in flight
        #pragma unroll
        for (int k = 0; k < 8; ++k)
            w[k] *= dinv[s[k]];                    // dn folded to epilogue
        #pragma unroll
        for (int k = 0; k < 8; ++k) {
            bffma(aA[k & 3], w[k], u[k].x);
            bffma(aB[k & 3], w[k], u[k].y);
        }
    }

    {
        int r = wave * 2 + sub;
        float4 bb = ((const float4*)b1)[rl];
        float4 v;
        v.x = fmaxf(fmaf(dn, (aA[0].x + aA[1].x) + (aA[2].x + aA[3].x), bb.x), 0.f);
        v.y = fmaxf(fmaf(dn, (aA[0].y + aA[1].y) + (aA[2].y + aA[3].y), bb.y), 0.f);
        v.z = fmaxf(fmaf(dn, (aB[0].x + aB[1].x) + (aB[2].x + aB[3].x), bb.z), 0.f);
        v.w = fmaxf(fmaf(dn, (aB[0].y + aB[1].y) + (aB[2].y + aB[3].y), bb.w), 0.f);
        ((float4*)rowbuf)[r * 33 + rl] = v;
    }
    __syncthreads();

    if (t < 128) {
        int f = t & 15, r = t >> 4;
        const float4* W4 = (const float4*)W2T;
        const float4* rb4 = (const float4*)rowbuf;
        float acc = 0.f;
        #pragma unroll 8
        for (int k4 = 0; k4 < 32; ++k4) {
            float4 w = W4[f * 33 + k4];
            float4 xv = rb4[r * 33 + k4];
            acc = fmaf(xv.x, w.x, acc);
            acc = fmaf(xv.y, w.y, acc);
            acc = fmaf(xv.z, w.z, acc);
            acc = fmaf(xv.w, w.w, acc);
        }
        int rn = rowbase + r;
        if (rn < N) h2[(size_t)rn * 16 + f] = bf16rn(acc);
    }
}

// ---- L6: pull2 + log_softmax, 4-deep unroll -------------------------------
__global__ __launch_bounds__(256) void k_pull2(
    const int* __restrict__ rs, const u16* __restrict__ ssrc,
    const float* __restrict__ dinv, const uint32* __restrict__ h2,
    const float* __restrict__ b2, float* __restrict__ out, int N)
{
    int idx = blockIdx.x * 256 + threadIdx.x;
    int n = idx >> 3;
    if (n >= N) return;
    int c = idx & 7;
    int start = (n == 0) ? 0 : rs[n - 1];
    int len = rs[n] - start;
    float dn = dinv[n];

    float2 a[4];
    #pragma unroll
    for (int k = 0; k < 4; ++k) a[k] = (float2){0.f, 0.f};

    for (int tt = 0; tt < len; tt += 4) {
        int s[4];
        uint32 u[4];
        float w[4];
        #pragma unroll
        for (int k = 0; k < 4; ++k) {
            bool act = (tt + k) < len;
            int jj = act ? (start + tt + k) : 0;   // index 0 always valid
            s[k] = (int)ssrc[jj];
            w[k] = act ? 1.f : 0.f;
        }
        #pragma unroll
        for (int k = 0; k < 4; ++k)
            u[k] = h2[(size_t)s[k] * 8 + c];
        #pragma unroll
        for (int k = 0; k < 4; ++k)
            w[k] *= dn * dinv[s[k]];
        #pragma unroll
        for (int k = 0; k < 4; ++k)
            bffma(a[k], w[k], u[k]);
    }

    float acc0 = (a[0].x + a[1].x) + (a[2].x + a[3].x);
    float acc1 = (a[0].y + a[1].y) + (a[2].y + a[3].y);
    float v0 = acc0 + b2[2 * c];
    float v1 = acc1 + b2[2 * c + 1];
    float m = fmaxf(v0, v1);
    #pragma unroll
    for (int off = 1; off < 8; off <<= 1) m = fmaxf(m, __shfl_xor(m, off));
    float s = expf(v0 - m) + expf(v1 - m);
    #pragma unroll
    for (int off = 1; off < 8; off <<= 1) s += __shfl_xor(s, off);
    float ls = logf(s);
    float2 r = {v0 - m - ls, v1 - m - ls};
    ((float2*)out)[(size_t)n * 8 + c] = r;
}

extern "C" void kernel_launch(void* const* d_in, const int* in_sizes, int n_in,
                              void* d_out, int out_size, void* d_ws, size_t ws_size,
                              hipStream_t stream) {
    const float* x  = (const float*)d_in[0];
    const int*   ei = (const int*)d_in[1];
    const float* W1 = (const float*)d_in[2];
    const float* b1 = (const float*)d_in[3];
    const float* W2 = (const float*)d_in[4];
    const float* b2 = (const float*)d_in[5];
    float* outp = (float*)d_out;

    const int E = in_sizes[1] / 2;
    const int N = in_sizes[0] / 128;   // N=50000 (fits u16 src packing)
    const int NB = (N + 255) >> 8;
    const int NH = (E + EH - 1) / EH;
    const int ntile = (N + 127) / 128; // 128-row tiles
    const int* src  = ei;
    const int* dstv = ei + E;

    const int Npad = (N + 255) & ~255;
    const int Epad = (E + 255) & ~255;
    int*   gh    = (int*)d_ws;                      // [NBMAX] global hist
    int*   bbase = gh + NBMAX;                      // [NBMAX+1] (+pad)
    int*   bfill = bbase + NBMAX + 256;             // [NBMAX]
    int*   rs    = bfill + NBMAX;                   // [Npad]
    float* dinv  = (float*)(rs + Npad);             // [Npad]
    uint32* tmp  = (uint32*)(dinv + Npad);          // [Epad] packed src|dstlow
    u16*   ssrc  = (u16*)(tmp + Epad);              // [Epad] u16
    uintptr_t hp = ((uintptr_t)(ssrc + Epad) + 255) & ~(uintptr_t)255;
    u16*   h     = (u16*)hp;                        // [Npad*128] bf16
    u16*   h2    = h + (size_t)Npad * 128;          // [Npad*16] bf16

    hipMemsetAsync(gh, 0, NBMAX * sizeof(int), stream);
    k_combo<<<NH + ntile, 256, 0, stream>>>(x, W1, dstv, gh, h, N, E, NB, NH);
    k_scanB<<<1, 1024, 0, stream>>>(gh, bbase, bfill, NB, E);
    k_partition<<<(E + CHUNK - 1) / CHUNK, 512, 0, stream>>>(src, dstv, bbase,
                                                             bfill, tmp, E, NB);
    k_bsort<<<NB, 1024, 0, stream>>>(tmp, bbase, ssrc, rs, dinv, N);
    k_pullg<<<(N + 7) / 8, 256, 0, stream>>>(rs, ssrc, dinv, (const uint2*)h,
                                             b1, W2, h2, N);
    k_pull2<<<(N * 8 + 255) / 256, 256, 0, stream>>>(rs, ssrc, dinv,
                                                     (const uint32*)h2, b2, outp, N);
}

// Round 15
// 166.164 us; speedup vs baseline: 1.2076x; 1.0157x over previous
//
#include <hip/hip_runtime.h>

// GCN 2-layer forward — R29 = R28 base + combo full-width (512-thr) blocks.
// R28 WIN (168.8, best): hist-first + 128-row shared-staging tiles, -3.3us.
// R29: combo's two 64-row halves ran SEQUENTIALLY in a 256-thr block (only
// 4 waves of x-loads in flight; half 2 waits on half 1). Now 512 thr /
// 8 waves, each wave owns 16 of the 128 rows CONCURRENTLY; W staged once by
// all 512 (staging time halved again). Same fragments, same rounding ->
// bit-identical h. LDS 34.8KB -> 4 blocks/CU x 512 = full 2048 thr/CU.
// Session history: parallelism-shaped changes pay (R20/R28); busy-work
// shaving on latency-bound blocks is null (R21/R24/R25/R26); pullg frozen
// at R25 form (5 variants adjudicated: 35us floor). If R29 null -> plateau.
// Pipeline: memset(gh) -> combo(hist first || gemm1) -> scanB -> partition
//           -> bsort -> pullg -> pull2+lsm

typedef unsigned int uint32;
typedef unsigned short u16;
typedef __attribute__((ext_vector_type(8))) short bf16x8;
typedef __attribute__((ext_vector_type(4))) float f32x4;

#define NBMAX 1024
#define CHUNK 2048
#define EH 8192   // edges per hist block

__device__ inline u16 bf16rn(float f) {
    unsigned u = __float_as_uint(f);
    return (u16)((u + 0x7fffu + ((u >> 16) & 1u)) >> 16);
}

__device__ inline void bffma(float2& a, float w, uint32 u) {
    a.x = fmaf(w, __uint_as_float(u << 16), a.x);
    a.y = fmaf(w, __uint_as_float(u & 0xffff0000u), a.y);
}

// ---- L1: hist blocks FIRST || gemm1 128-row tiles, 8 concurrent waves -----
__global__ __launch_bounds__(512) void k_combo(
    const float* __restrict__ x, const float* __restrict__ W1,
    const int* __restrict__ dstv, int* __restrict__ gh,
    u16* __restrict__ h, int N, int E, int NB, int NH)
{
    __shared__ __align__(16) unsigned char smem[128 * 136 * 2];  // 34816 B
    int t = threadIdx.x;

    if ((int)blockIdx.x < NH) {        // hist blocks first: co-run with gemm
        int* hl = (int*)smem;
        int hb = blockIdx.x;
        int e0 = hb * EH, e1 = min(e0 + EH, E);
        for (int i = t; i < NB; i += 512) hl[i] = 0;
        __syncthreads();
        for (int e = e0 + t; e < e1; e += 512)
            atomicAdd(&hl[dstv[e] >> 8], 1);
        __syncthreads();
        for (int i = t; i < NB; i += 512) {
            int c = hl[i];
            if (c) atomicAdd(&gh[i], c);   // ~196 device atomics/block (cheap)
        }
        return;
    }

    // gemm1: h[N,128](bf16) = x @ W1, MFMA 16x16x32, operands swapped:
    // D[feature][node]; lane owns node=rowbase+ln, features ct*16+quad*4+i.
    // 8 waves x 16 rows = 128-row tile, all concurrent, ONE W staging.
    u16* Wl = (u16*)smem;  // [n][k] pitch 136 (2-way bank aliasing: free)
    const float4* Wg4 = (const float4*)W1;
    for (int g = t; g < 128 * 32; g += 512) {
        int k = g >> 5, n4 = (g & 31) * 4;
        float4 v = Wg4[g];
        Wl[(n4 + 0) * 136 + k] = bf16rn(v.x);
        Wl[(n4 + 1) * 136 + k] = bf16rn(v.y);
        Wl[(n4 + 2) * 136 + k] = bf16rn(v.z);
        Wl[(n4 + 3) * 136 + k] = bf16rn(v.w);
    }
    __syncthreads();

    int wave = t >> 6, lane = t & 63;
    int quad = lane >> 4, ln = lane & 15;
    int rowbase = (blockIdx.x - NH) * 128 + wave * 16;
    int node = rowbase + ln;
    int rclamp = min(node, N - 1);

    f32x4 acc[8];
    #pragma unroll
    for (int ct = 0; ct < 8; ++ct) acc[ct] = (f32x4){0.f, 0.f, 0.f, 0.f};

    #pragma unroll
    for (int q = 0; q < 4; ++q) {
        const float4* xr = (const float4*)(x + (size_t)rclamp * 128 + q * 32 + quad * 8);
        float4 a0 = xr[0], a1 = xr[1];
        bf16x8 xfr;   // B-operand: col=node(ln), k = q*32 + quad*8 + e
        xfr[0] = (short)bf16rn(a0.x); xfr[1] = (short)bf16rn(a0.y);
        xfr[2] = (short)bf16rn(a0.z); xfr[3] = (short)bf16rn(a0.w);
        xfr[4] = (short)bf16rn(a1.x); xfr[5] = (short)bf16rn(a1.y);
        xfr[6] = (short)bf16rn(a1.z); xfr[7] = (short)bf16rn(a1.w);
        #pragma unroll
        for (int ct = 0; ct < 8; ++ct) {
            // A-operand: row=feature-in-block(ln), k = q*32 + quad*8 + e
            bf16x8 wfr = *(const bf16x8*)&Wl[(ct * 16 + ln) * 136 + q * 32 + quad * 8];
            acc[ct] = __builtin_amdgcn_mfma_f32_16x16x32_bf16(wfr, xfr, acc[ct], 0, 0, 0);
        }
    }
    if (node < N) {
        u16* hp = h + (size_t)node * 128 + quad * 4;
        #pragma unroll
        for (int ct = 0; ct < 8; ++ct) {
            uint2 v;
            v.x = (uint32)bf16rn(acc[ct][0]) | ((uint32)bf16rn(acc[ct][1]) << 16);
            v.y = (uint32)bf16rn(acc[ct][2]) | ((uint32)bf16rn(acc[ct][3]) << 16);
            *(uint2*)(hp + ct * 16) = v;
        }
    }
}

// ---- L2: exclusive scan of gh via shfl wave-scan (2 barriers) -------------
__global__ __launch_bounds__(1024) void k_scanB(
    const int* __restrict__ gh, int* __restrict__ bbase,
    int* __restrict__ bfill, int NB, int E)
{
    __shared__ int wsum[16];
    int t = threadIdx.x;
    int lane = t & 63, wv = t >> 6;
    int v = (t < NB) ? gh[t] : 0;
    int sc = v;
    #pragma unroll
    for (int off = 1; off < 64; off <<= 1) {
        int u = __shfl_up(sc, off);
        if (lane >= off) sc += u;
    }
    if (lane == 63) wsum[wv] = sc;
    __syncthreads();
    if (wv == 0 && lane < 16) {
        int b = wsum[lane];
        int bs = b;
        #pragma unroll
        for (int off = 1; off < 16; off <<= 1) {
            int u = __shfl_up(bs, off);
            if (lane >= off) bs += u;
        }
        wsum[lane] = bs - b;   // exclusive prefix of wave sums
    }
    __syncthreads();
    int incl = sc + wsum[wv];
    if (t < NB) {
        bbase[t] = incl - v;
        bfill[t] = 0;
    }
    if (t == 0) bbase[NB] = E;
}

// ---- L3: partition edges into bucket regions (512 thr, CHUNK 2048) --------
__global__ __launch_bounds__(512) void k_partition(
    const int* __restrict__ src, const int* __restrict__ dstv,
    const int* __restrict__ bbase, int* __restrict__ bfill,
    uint32* __restrict__ tmp, int E, int NB)
{
    __shared__ int cntL[NBMAX];
    __shared__ int baseL[NBMAX];
    int t = threadIdx.x;
    int e0 = blockIdx.x * CHUNK;
    int e1 = min(e0 + CHUNK, E);
    for (int i = t; i < NB; i += 512) cntL[i] = 0;
    __syncthreads();
    for (int e = e0 + t; e < e1; e += 512)
        atomicAdd(&cntL[dstv[e] >> 8], 1);
    __syncthreads();
    for (int i = t; i < NB; i += 512) {
        int cc = cntL[i];
        baseL[i] = cc ? bbase[i] + atomicAdd(&bfill[i], cc) : 0;
        cntL[i] = 0;
    }
    __syncthreads();
    for (int e = e0 + t; e < e1; e += 512) {
        int sv = src[e], d = dstv[e];
        int b = d >> 8;
        int r = atomicAdd(&cntL[b], 1);
        tmp[baseL[b] + r] = (uint32)sv | ((uint32)(d & 255) << 16);
    }
}

// ---- L4: per-bucket exact sort (1024 threads); emit dinv / rs / ssrc ------
__global__ __launch_bounds__(1024) void k_bsort(
    const uint32* __restrict__ tmp, const int* __restrict__ bbase,
    u16* __restrict__ ssrc, int* __restrict__ rs,
    float* __restrict__ dinv, int N)
{
    __shared__ int cnt[256];
    __shared__ int ofs[256];
    int t = threadIdx.x;
    int b = blockIdx.x;
    int base = bbase[b];
    int endb = bbase[b + 1];
    int node0 = b << 8;

    if (t < 256) cnt[t] = 0;
    __syncthreads();
    for (int i = base + t; i < endb; i += 1024)
        atomicAdd(&cnt[(tmp[i] >> 16) & 255], 1);
    __syncthreads();
    int v = (t < 256) ? cnt[t] : 0;
    __syncthreads();
    for (int off = 1; off < 256; off <<= 1) {
        int u = (t >= off && t < 256) ? cnt[t - off] : 0;
        __syncthreads();
        if (t < 256) cnt[t] += u;
        __syncthreads();
    }
    if (t < 256) {
        int node = node0 + t;
        if (node < N) {
            dinv[node] = rsqrtf(fmaxf((float)v, 1.0f));
            rs[node] = base + cnt[t];
        }
        ofs[t] = base + cnt[t] - v;
    }
    __syncthreads();
    for (int i = base + t; i < endb; i += 1024) {
        uint32 rec = tmp[i];
        int pos = atomicAdd(&ofs[(rec >> 16) & 255], 1);
        ssrc[pos] = (u16)(rec & 0xffffu);
    }
}

// ---- L5: pullg — fused pull1 + gemm2; 8-deep gather (R25 form, frozen) ----
__global__ __launch_bounds__(256) void k_pullg(
    const int* __restrict__ rs, const u16* __restrict__ ssrc,
    const float* __restrict__ dinv, const uint2* __restrict__ h,
    const float* __restrict__ b1, const float* __restrict__ W2,
    u16* __restrict__ h2, int N)
{
    __shared__ float W2T[16 * 132];   // [f][k] pitch 132
    __shared__ float rowbuf[8 * 132]; // [r][k] pitch 132 (float4 pitch 33)
    int t = threadIdx.x;

    for (int g = t; g < 2048; g += 256) {
        int k = g >> 4, f = g & 15;
        W2T[f * 132 + k] = W2[g];
    }

    int wave = t >> 6, lane = t & 63;
    int sub = lane >> 5;
    int rl = lane & 31;
    int rowbase = blockIdx.x * 8;
    int n = rowbase + wave * 2 + sub;
    bool valid = (n < N);
    int nc = valid ? n : 0;
    int start = valid ? ((nc == 0) ? 0 : rs[nc - 1]) : 0;
    int len   = valid ? (rs[nc] - start) : 0;
    float dn  = valid ? dinv[nc] : 0.f;
    int lenMax = max(len, __shfl_xor(len, 32));

    float2 aA[4], aB[4];
    #pragma unroll
    for (int k = 0; k < 4; ++k) {
        aA[k] = (float2){0.f, 0.f};
        aB[k] = (float2){0.f, 0.f};
    }

    for (int tt = 0; tt < lenMax; tt += 8) {
        int s[8];
        uint2 u[8];
        float w[8];
        #pragma unroll
        for (int k = 0; k < 8; ++k) {
            bool act = (tt + k) < len;
            int jj = act ? (start + tt + k) : 0;   // index 0 always valid
            s[k] = (int)ssrc[jj];
            w[k] = act ? 1.f : 0.f;
        }
        #pragma unroll
        for (int k = 0; k < 8; ++k)
            u[k] = h[(size_t)s[k] * 32 + rl];      // 8 gathers in flight
        #pragma unroll
        for (int k = 0; k < 8; ++k)
            w[k] *= dinv[s[k]];                    // dn folded to epilogue
        #pragma unroll
        for (int k = 0; k < 8; ++k) {
            bffma(aA[k & 3], w[k], u[k].x);
            bffma(aB[k & 3], w[k], u[k].y);
        }
    }

    {
        int r = wave * 2 + sub;
        float4 bb = ((const float4*)b1)[rl];
        float4 v;
        v.x = fmaxf(fmaf(dn, (aA[0].x + aA[1].x) + (aA[2].x + aA[3].x), bb.x), 0.f);
        v.y = fmaxf(fmaf(dn, (aA[0].y + aA[1].y) + (aA[2].y + aA[3].y), bb.y), 0.f);
        v.z = fmaxf(fmaf(dn, (aB[0].x + aB[1].x) + (aB[2].x + aB[3].x), bb.z), 0.f);
        v.w = fmaxf(fmaf(dn, (aB[0].y + aB[1].y) + (aB[2].y + aB[3].y), bb.w), 0.f);
        ((float4*)rowbuf)[r * 33 + rl] = v;
    }
    __syncthreads();

    if (t < 128) {
        int f = t & 15, r = t >> 4;
        const float4* W4 = (const float4*)W2T;
        const float4* rb4 = (const float4*)rowbuf;
        float acc = 0.f;
        #pragma unroll 8
        for (int k4 = 0; k4 < 32; ++k4) {
            float4 w = W4[f * 33 + k4];
            float4 xv = rb4[r * 33 + k4];
            acc = fmaf(xv.x, w.x, acc);
            acc = fmaf(xv.y, w.y, acc);
            acc = fmaf(xv.z, w.z, acc);
            acc = fmaf(xv.w, w.w, acc);
        }
        int rn = rowbase + r;
        if (rn < N) h2[(size_t)rn * 16 + f] = bf16rn(acc);
    }
}

// ---- L6: pull2 + log_softmax, 4-deep unroll -------------------------------
__global__ __launch_bounds__(256) void k_pull2(
    const int* __restrict__ rs, const u16* __restrict__ ssrc,
    const float* __restrict__ dinv, const uint32* __restrict__ h2,
    const float* __restrict__ b2, float* __restrict__ out, int N)
{
    int idx = blockIdx.x * 256 + threadIdx.x;
    int n = idx >> 3;
    if (n >= N) return;
    int c = idx & 7;
    int start = (n == 0) ? 0 : rs[n - 1];
    int len = rs[n] - start;
    float dn = dinv[n];

    float2 a[4];
    #pragma unroll
    for (int k = 0; k < 4; ++k) a[k] = (float2){0.f, 0.f};

    for (int tt = 0; tt < len; tt += 4) {
        int s[4];
        uint32 u[4];
        float w[4];
        #pragma unroll
        for (int k = 0; k < 4; ++k) {
            bool act = (tt + k) < len;
            int jj = act ? (start + tt + k) : 0;   // index 0 always valid
            s[k] = (int)ssrc[jj];
            w[k] = act ? 1.f : 0.f;
        }
        #pragma unroll
        for (int k = 0; k < 4; ++k)
            u[k] = h2[(size_t)s[k] * 8 + c];
        #pragma unroll
        for (int k = 0; k < 4; ++k)
            w[k] *= dn * dinv[s[k]];
        #pragma unroll
        for (int k = 0; k < 4; ++k)
            bffma(a[k], w[k], u[k]);
    }

    float acc0 = (a[0].x + a[1].x) + (a[2].x + a[3].x);
    float acc1 = (a[0].y + a[1].y) + (a[2].y + a[3].y);
    float v0 = acc0 + b2[2 * c];
    float v1 = acc1 + b2[2 * c + 1];
    float m = fmaxf(v0, v1);
    #pragma unroll
    for (int off = 1; off < 8; off <<= 1) m = fmaxf(m, __shfl_xor(m, off));
    float s = expf(v0 - m) + expf(v1 - m);
    #pragma unroll
    for (int off = 1; off < 8; off <<= 1) s += __shfl_xor(s, off);
    float ls = logf(s);
    float2 r = {v0 - m - ls, v1 - m - ls};
    ((float2*)out)[(size_t)n * 8 + c] = r;
}

extern "C" void kernel_launch(void* const* d_in, const int* in_sizes, int n_in,
                              void* d_out, int out_size, void* d_ws, size_t ws_size,
                              hipStream_t stream) {
    const float* x  = (const float*)d_in[0];
    const int*   ei = (const int*)d_in[1];
    const float* W1 = (const float*)d_in[2];
    const float* b1 = (const float*)d_in[3];
    const float* W2 = (const float*)d_in[4];
    const float* b2 = (const float*)d_in[5];
    float* outp = (float*)d_out;

    const int E = in_sizes[1] / 2;
    const int N = in_sizes[0] / 128;   // N=50000 (fits u16 src packing)
    const int NB = (N + 255) >> 8;
    const int NH = (E + EH - 1) / EH;
    const int ntile = (N + 127) / 128; // 128-row tiles
    const int* src  = ei;
    const int* dstv = ei + E;

    const int Npad = (N + 255) & ~255;
    const int Epad = (E + 255) & ~255;
    int*   gh    = (int*)d_ws;                      // [NBMAX] global hist
    int*   bbase = gh + NBMAX;                      // [NBMAX+1] (+pad)
    int*   bfill = bbase + NBMAX + 256;             // [NBMAX]
    int*   rs    = bfill + NBMAX;                   // [Npad]
    float* dinv  = (float*)(rs + Npad);             // [Npad]
    uint32* tmp  = (uint32*)(dinv + Npad);          // [Epad] packed src|dstlow
    u16*   ssrc  = (u16*)(tmp + Epad);              // [Epad] u16
    uintptr_t hp = ((uintptr_t)(ssrc + Epad) + 255) & ~(uintptr_t)255;
    u16*   h     = (u16*)hp;                        // [Npad*128] bf16
    u16*   h2    = h + (size_t)Npad * 128;          // [Npad*16] bf16

    hipMemsetAsync(gh, 0, NBMAX * sizeof(int), stream);
    k_combo<<<NH + ntile, 512, 0, stream>>>(x, W1, dstv, gh, h, N, E, NB, NH);
    k_scanB<<<1, 1024, 0, stream>>>(gh, bbase, bfill, NB, E);
    k_partition<<<(E + CHUNK - 1) / CHUNK, 512, 0, stream>>>(src, dstv, bbase,
                                                             bfill, tmp, E, NB);
    k_bsort<<<NB, 1024, 0, stream>>>(tmp, bbase, ssrc, rs, dinv, N);
    k_pullg<<<(N + 7) / 8, 256, 0, stream>>>(rs, ssrc, dinv, (const uint2*)h,
                                             b1, W2, h2, N);
    k_pull2<<<(N * 8 + 255) / 256, 256, 0, stream>>>(rs, ssrc, dinv,
                                                     (const uint32*)h2, b2, outp, N);
}